// Round 1
// baseline (24473.396 us; speedup 1.0000x reference)
//
#include <hip/hip_runtime.h>

#define DDIM 2048
#define BDIM 512
#define NELEM (BDIM * DDIM)
#define NV4 (NELEM / 4)

// scalar slots (floats/uints at ws + 8*NELEM)
#define SC_DT 0
#define SC_DONE 1
#define SC_ERR 2
#define SC_SP 3
#define SC_COMMIT 4

#define TOLF 0.01f
#define MIN_DTF 0.1f
#define SPEED_TOLF 1e-3f

__device__ __forceinline__ float reflect_y(float v) {
    int i = (int)v;  // trunc toward zero, same as jnp astype(int32)
    return ((i & 1) == 0) ? v : 1.0f - v;  // (i&1) matches python floor-mod-2
}

__device__ __forceinline__ float4 f4_scale(float c, float4 a) {
    return make_float4(c * a.x, c * a.y, c * a.z, c * a.w);
}
__device__ __forceinline__ float4 f4_fma(float c, float4 a, float4 b) {  // c*a + b
    return make_float4(fmaf(c, a.x, b.x), fmaf(c, a.y, b.y), fmaf(c, a.z, b.z), fmaf(c, a.w, b.w));
}

__global__ void init_kernel(const float* __restrict__ x0, float* __restrict__ x,
                            float* __restrict__ scal) {
    int tid = blockIdx.x * blockDim.x + threadIdx.x;
    const float4* src = (const float4*)x0;
    float4* dst = (float4*)x;
    for (int i = tid; i < NV4; i += gridDim.x * blockDim.x) dst[i] = src[i];
    if (tid == 0) {
        scal[SC_DT] = 0.1f;
        ((unsigned int*)scal)[SC_DONE] = 0u;
        scal[SC_ERR] = 0.0f;
        scal[SC_SP] = 0.0f;
        ((unsigned int*)scal)[SC_COMMIT] = 0u;
    }
}

template <int NK>
__global__ void prep_kernel(const float* __restrict__ x, const float* __restrict__ scal,
                            const float* __restrict__ k1, const float* __restrict__ k2,
                            const float* __restrict__ k3, const float* __restrict__ k4,
                            const float* __restrict__ k5, float c1, float c2, float c3, float c4,
                            float c5, float* __restrict__ xs) {
    float dt = scal[SC_DT];
    int tid = blockIdx.x * blockDim.x + threadIdx.x;
    const float4* X = (const float4*)x;
    const float4* K1 = (const float4*)k1;
    const float4* K2 = (const float4*)k2;
    const float4* K3 = (const float4*)k3;
    const float4* K4 = (const float4*)k4;
    const float4* K5 = (const float4*)k5;
    float4* XS = (float4*)xs;
    for (int i = tid; i < NV4; i += gridDim.x * blockDim.x) {
        float4 s = f4_scale(c1, K1[i]);
        if (NK >= 2) s = f4_fma(c2, K2[i], s);
        if (NK >= 3) s = f4_fma(c3, K3[i], s);
        if (NK >= 4) s = f4_fma(c4, K4[i], s);
        if (NK >= 5) s = f4_fma(c5, K5[i], s);
        float4 xv = X[i];
        XS[i] = f4_fma(dt, s, xv);
    }
}

// kout = sign(xs) * ( g(xs) @ W + bias ),  g = boundary reflect, sign = dg/dx
__global__ __launch_bounds__(256) void stage_gemm(const float* __restrict__ xs,
                                                  const float* __restrict__ W,
                                                  const float* __restrict__ bias,
                                                  float* __restrict__ kout) {
    __shared__ float As[16][68];  // transposed A tile [k][m], padded for banks + f4 align
    __shared__ float Bs[16][64];
    const int tid = threadIdx.x;
    const int n0 = blockIdx.x * 64;
    const int m0 = blockIdx.y * 64;
    const int tm = tid >> 4;         // 0..15
    const int tn = tid & 15;         // 0..15
    const int am = tid >> 2;         // 0..63
    const int ak = (tid & 3) << 2;   // 0,4,8,12
    const int bk = tid >> 4;         // 0..15
    const int bn = (tid & 15) << 2;  // 0..60

    const float* aptr = xs + (size_t)(m0 + am) * DDIM + ak;
    const float* bptr = W + (size_t)bk * DDIM + n0 + bn;

    float acc[4][4];
#pragma unroll
    for (int i = 0; i < 4; ++i)
#pragma unroll
        for (int j = 0; j < 4; ++j) acc[i][j] = 0.0f;

    for (int kt = 0; kt < DDIM; kt += 16) {
        float4 av = *(const float4*)(aptr + kt);
        float4 bv = *(const float4*)(bptr + (size_t)kt * DDIM);
        __syncthreads();
        As[ak + 0][am] = reflect_y(av.x);
        As[ak + 1][am] = reflect_y(av.y);
        As[ak + 2][am] = reflect_y(av.z);
        As[ak + 3][am] = reflect_y(av.w);
        *(float4*)&Bs[bk][bn] = bv;
        __syncthreads();
#pragma unroll
        for (int k = 0; k < 16; ++k) {
            float4 a = *(const float4*)&As[k][tm << 2];
            float4 b = *(const float4*)&Bs[k][tn << 2];
            acc[0][0] = fmaf(a.x, b.x, acc[0][0]);
            acc[0][1] = fmaf(a.x, b.y, acc[0][1]);
            acc[0][2] = fmaf(a.x, b.z, acc[0][2]);
            acc[0][3] = fmaf(a.x, b.w, acc[0][3]);
            acc[1][0] = fmaf(a.y, b.x, acc[1][0]);
            acc[1][1] = fmaf(a.y, b.y, acc[1][1]);
            acc[1][2] = fmaf(a.y, b.z, acc[1][2]);
            acc[1][3] = fmaf(a.y, b.w, acc[1][3]);
            acc[2][0] = fmaf(a.z, b.x, acc[2][0]);
            acc[2][1] = fmaf(a.z, b.y, acc[2][1]);
            acc[2][2] = fmaf(a.z, b.z, acc[2][2]);
            acc[2][3] = fmaf(a.z, b.w, acc[2][3]);
            acc[3][0] = fmaf(a.w, b.x, acc[3][0]);
            acc[3][1] = fmaf(a.w, b.y, acc[3][1]);
            acc[3][2] = fmaf(a.w, b.z, acc[3][2]);
            acc[3][3] = fmaf(a.w, b.w, acc[3][3]);
        }
    }

    float4 bb = *(const float4*)&bias[n0 + (tn << 2)];
#pragma unroll
    for (int i = 0; i < 4; ++i) {
        int gm = m0 + (tm << 2) + i;
        const float* xrow = xs + (size_t)gm * DDIM + n0 + (tn << 2);
        float4 o;
        {
            int c = (int)xrow[0];
            float s = ((c & 1) == 0) ? 1.0f : -1.0f;
            o.x = s * (acc[i][0] + bb.x);
        }
        {
            int c = (int)xrow[1];
            float s = ((c & 1) == 0) ? 1.0f : -1.0f;
            o.y = s * (acc[i][1] + bb.y);
        }
        {
            int c = (int)xrow[2];
            float s = ((c & 1) == 0) ? 1.0f : -1.0f;
            o.z = s * (acc[i][2] + bb.z);
        }
        {
            int c = (int)xrow[3];
            float s = ((c & 1) == 0) ? 1.0f : -1.0f;
            o.w = s * (acc[i][3] + bb.w);
        }
        *(float4*)&kout[(size_t)gm * DDIM + n0 + (tn << 2)] = o;
    }
}

__global__ __launch_bounds__(256) void finish_kernel(
    const float* __restrict__ x, const float* __restrict__ k1, const float* __restrict__ k3,
    const float* __restrict__ k4, const float* __restrict__ k5, const float* __restrict__ k6,
    float* __restrict__ x5out, float* scal) {
    const float C51 = (float)(16.0 / 135.0), C53 = (float)(6656.0 / 12825.0),
                C54 = (float)(28561.0 / 56430.0), C55 = (float)(-9.0 / 50.0),
                C56 = (float)(2.0 / 55.0);
    const float C41 = (float)(25.0 / 216.0), C43 = (float)(1408.0 / 2565.0),
                C44 = (float)(2197.0 / 4104.0), C45 = (float)(-1.0 / 5.0);
    float dt = scal[SC_DT];
    int tid = blockIdx.x * blockDim.x + threadIdx.x;
    const float4* X = (const float4*)x;
    const float4* K1 = (const float4*)k1;
    const float4* K3 = (const float4*)k3;
    const float4* K4 = (const float4*)k4;
    const float4* K5 = (const float4*)k5;
    const float4* K6 = (const float4*)k6;
    float4* X5 = (float4*)x5out;
    float lerr = 0.0f, lsp = 0.0f;
    for (int i = tid; i < NV4; i += gridDim.x * blockDim.x) {
        float4 xv = X[i], a = K1[i], c = K3[i], d = K4[i], e = K5[i], f = K6[i];
        float4 s5 = f4_scale(C51, a);
        s5 = f4_fma(C53, c, s5);
        s5 = f4_fma(C54, d, s5);
        s5 = f4_fma(C55, e, s5);
        s5 = f4_fma(C56, f, s5);
        float4 s4 = f4_scale(C41, a);
        s4 = f4_fma(C43, c, s4);
        s4 = f4_fma(C44, d, s4);
        s4 = f4_fma(C45, e, s4);
        float4 v5 = f4_fma(dt, s5, xv);
        float4 v4 = f4_fma(dt, s4, xv);
        lerr = fmaxf(lerr, fabsf(v5.x - v4.x));
        lerr = fmaxf(lerr, fabsf(v5.y - v4.y));
        lerr = fmaxf(lerr, fabsf(v5.z - v4.z));
        lerr = fmaxf(lerr, fabsf(v5.w - v4.w));
        lsp = fmaxf(lsp, fabsf(v5.x - xv.x));
        lsp = fmaxf(lsp, fabsf(v5.y - xv.y));
        lsp = fmaxf(lsp, fabsf(v5.z - xv.z));
        lsp = fmaxf(lsp, fabsf(v5.w - xv.w));
        X5[i] = v5;
    }
#pragma unroll
    for (int off = 32; off > 0; off >>= 1) {
        lerr = fmaxf(lerr, __shfl_down(lerr, off));
        lsp = fmaxf(lsp, __shfl_down(lsp, off));
    }
    __shared__ float serr[4], ssp[4];
    int wid = threadIdx.x >> 6;
    if ((threadIdx.x & 63) == 0) {
        serr[wid] = lerr;
        ssp[wid] = lsp;
    }
    __syncthreads();
    if (threadIdx.x == 0) {
        float e = fmaxf(fmaxf(serr[0], serr[1]), fmaxf(serr[2], serr[3]));
        float s = fmaxf(fmaxf(ssp[0], ssp[1]), fmaxf(ssp[2], ssp[3]));
        atomicMax((unsigned int*)&scal[SC_ERR], __float_as_uint(e));
        atomicMax((unsigned int*)&scal[SC_SP], __float_as_uint(s));
    }
}

__global__ void scalar_update(float* scal) {
    if (threadIdx.x == 0 && blockIdx.x == 0) {
        float dt = scal[SC_DT];
        float err = scal[SC_ERR];
        float spmax = scal[SC_SP];
        unsigned int done = ((unsigned int*)scal)[SC_DONE];
        bool accept = err < TOLF;
        bool step = accept && (done == 0u);
        float speed = spmax / dt;
        unsigned int done_new = (done || (step && (speed < SPEED_TOLF))) ? 1u : 0u;
        float scale = 0.9f * powf(TOLF / (err + 1e-12f), 0.2f);
        scale = fminf(fmaxf(scale, 0.1f), 4.0f);
        float dtn = fmaxf(dt * scale, MIN_DTF);
        scal[SC_DT] = done ? dt : dtn;
        ((unsigned int*)scal)[SC_DONE] = done_new;
        ((unsigned int*)scal)[SC_COMMIT] = step ? 1u : 0u;
        scal[SC_ERR] = 0.0f;
        scal[SC_SP] = 0.0f;
    }
}

__global__ void commit_kernel(float* __restrict__ x, const float* __restrict__ x5,
                              const float* __restrict__ scal) {
    if (((const unsigned int*)scal)[SC_COMMIT] == 0u) return;
    int tid = blockIdx.x * blockDim.x + threadIdx.x;
    float4* X = (float4*)x;
    const float4* X5 = (const float4*)x5;
    for (int i = tid; i < NV4; i += gridDim.x * blockDim.x) X[i] = X5[i];
}

extern "C" void kernel_launch(void* const* d_in, const int* in_sizes, int n_in, void* d_out,
                              int out_size, void* d_ws, size_t ws_size, hipStream_t stream) {
    const float* x0 = (const float*)d_in[0];
    const float* W = (const float*)d_in[1];
    const float* bias = (const float*)d_in[2];
    float* x = (float*)d_out;
    float* ws = (float*)d_ws;
    float* k1 = ws + 0 * (size_t)NELEM;
    float* k2 = ws + 1 * (size_t)NELEM;
    float* k3 = ws + 2 * (size_t)NELEM;
    float* k4 = ws + 3 * (size_t)NELEM;
    float* k5 = ws + 4 * (size_t)NELEM;
    float* k6 = ws + 5 * (size_t)NELEM;
    float* x5 = ws + 6 * (size_t)NELEM;
    float* xs = ws + 7 * (size_t)NELEM;
    float* scal = ws + 8 * (size_t)NELEM;

    dim3 gg(DDIM / 64, BDIM / 64);

    init_kernel<<<1024, 256, 0, stream>>>(x0, x, scal);
    for (int it = 0; it < 32; ++it) {
        stage_gemm<<<gg, 256, 0, stream>>>(x, W, bias, k1);
        prep_kernel<1><<<1024, 256, 0, stream>>>(x, scal, k1, k1, k1, k1, k1, 0.25f, 0.0f, 0.0f,
                                                 0.0f, 0.0f, xs);
        stage_gemm<<<gg, 256, 0, stream>>>(xs, W, bias, k2);
        prep_kernel<2><<<1024, 256, 0, stream>>>(x, scal, k1, k2, k1, k1, k1,
                                                 (float)(3.0 / 32.0), (float)(9.0 / 32.0), 0.0f,
                                                 0.0f, 0.0f, xs);
        stage_gemm<<<gg, 256, 0, stream>>>(xs, W, bias, k3);
        prep_kernel<3><<<1024, 256, 0, stream>>>(
            x, scal, k1, k2, k3, k1, k1, (float)(1932.0 / 2197.0), (float)(-7200.0 / 2197.0),
            (float)(7296.0 / 2197.0), 0.0f, 0.0f, xs);
        stage_gemm<<<gg, 256, 0, stream>>>(xs, W, bias, k4);
        prep_kernel<4><<<1024, 256, 0, stream>>>(
            x, scal, k1, k2, k3, k4, k1, (float)(439.0 / 216.0), -8.0f, (float)(3680.0 / 513.0),
            (float)(-845.0 / 4104.0), 0.0f, xs);
        stage_gemm<<<gg, 256, 0, stream>>>(xs, W, bias, k5);
        prep_kernel<5><<<1024, 256, 0, stream>>>(
            x, scal, k1, k2, k3, k4, k5, (float)(-8.0 / 27.0), 2.0f, (float)(-3544.0 / 2565.0),
            (float)(1859.0 / 4104.0), (float)(-11.0 / 40.0), xs);
        stage_gemm<<<gg, 256, 0, stream>>>(xs, W, bias, k6);
        finish_kernel<<<1024, 256, 0, stream>>>(x, k1, k3, k4, k5, k6, x5, scal);
        scalar_update<<<1, 64, 0, stream>>>(scal);
        commit_kernel<<<1024, 256, 0, stream>>>(x, x5, scal);
    }
}

// Round 2
// 5619.049 us; speedup vs baseline: 4.3554x; 4.3554x over previous
//
#include <hip/hip_runtime.h>

#define DDIM 2048
#define BDIM 512
#define NELEM (BDIM * DDIM)
#define NV4 (NELEM / 4)
#define NW4 (DDIM * DDIM / 4)

#define SC_DT 0
#define SC_DONE 1
#define SC_ERR 2
#define SC_SP 3
#define SC_COMMIT 4

#define TOLF 0.01f
#define MIN_DTF 0.1f
#define SPEED_TOLF 1e-3f

typedef _Float16 half8 __attribute__((ext_vector_type(8)));
typedef _Float16 half4v __attribute__((ext_vector_type(4)));
typedef float f32x4 __attribute__((ext_vector_type(4)));

__device__ __forceinline__ void glds16(const _Float16* g, _Float16* l) {
    __builtin_amdgcn_global_load_lds((__attribute__((address_space(1))) void*)g,
                                     (__attribute__((address_space(3))) void*)l, 16, 0, 0);
}

__device__ __forceinline__ void split_f16(float y, _Float16& h, _Float16& l) {
    h = (_Float16)y;
    l = (_Float16)(y - (float)h);
}

__device__ __forceinline__ float reflect_f(float v) {
    int i = (int)v;
    return ((i & 1) == 0) ? v : 1.0f - v;
}

// ---------------- init / conversion kernels ----------------

__global__ void wconv_kernel(const float* __restrict__ W, _Float16* __restrict__ Wh,
                             _Float16* __restrict__ Wl) {
    int tid = blockIdx.x * blockDim.x + threadIdx.x;
    const float4* Wv = (const float4*)W;
    for (int i = tid; i < NW4; i += gridDim.x * blockDim.x) {
        float4 v = Wv[i];
        half4v h, l;
        float vv[4] = {v.x, v.y, v.z, v.w};
#pragma unroll
        for (int q = 0; q < 4; ++q) {
            _Float16 hh, ll;
            split_f16(vv[q], hh, ll);
            h[q] = hh;
            l[q] = ll;
        }
        *(half4v*)&Wh[(size_t)i * 4] = h;
        *(half4v*)&Wl[(size_t)i * 4] = l;
    }
}

__global__ void init_kernel(const float* __restrict__ x0, float* __restrict__ x,
                            _Float16* __restrict__ Ah, _Float16* __restrict__ Al,
                            float* __restrict__ scal) {
    int tid = blockIdx.x * blockDim.x + threadIdx.x;
    const float4* X0 = (const float4*)x0;
    float4* X = (float4*)x;
    for (int i = tid; i < NV4; i += gridDim.x * blockDim.x) {
        float4 v = X0[i];
        X[i] = v;
        half4v h, l;
        float vv[4] = {v.x, v.y, v.z, v.w};
#pragma unroll
        for (int q = 0; q < 4; ++q) {
            float y = reflect_f(vv[q]);
            _Float16 hh, ll;
            split_f16(y, hh, ll);
            h[q] = hh;
            l[q] = ll;
        }
        *(half4v*)&Ah[(size_t)i * 4] = h;
        *(half4v*)&Al[(size_t)i * 4] = l;
    }
    if (tid == 0) {
        scal[SC_DT] = 0.1f;
        ((unsigned int*)scal)[SC_DONE] = 0u;
        scal[SC_ERR] = 0.0f;
        scal[SC_SP] = 0.0f;
        ((unsigned int*)scal)[SC_COMMIT] = 0u;
    }
}

// ---------------- fused stage GEMM ----------------
// Computes kS = sign(xs_S) * (G(xs_S) @ W + bias) via split-f16 MFMA,
// then (S<6) prepares next stage's A = split(reflect(xs_{S+1})),
// or (S==6) computes x5/x4/err/speed reductions.

template <int S>
__global__ __launch_bounds__(256) void stage_kernel(
    const _Float16* __restrict__ Ah, const _Float16* __restrict__ Al,
    _Float16* __restrict__ Aoh, _Float16* __restrict__ Aol, const _Float16* __restrict__ Wh,
    const _Float16* __restrict__ Wl, const float* __restrict__ bias,
    const float* __restrict__ xg, const float* __restrict__ gk1, const float* __restrict__ gk2,
    const float* __restrict__ gk3, const float* __restrict__ gk4, const float* __restrict__ gk5,
    float* __restrict__ kout, float* __restrict__ x5out, float* __restrict__ scal) {
    __shared__ __align__(16) _Float16 lds[2][4][64 * 64];  // [buf][Ah,Al,Wh,Wl][row][k]
    __shared__ float serr[4], ssp[4];

    const int tid = threadIdx.x;
    const int li = tid & 63;
    const int wid = tid >> 6;
    const int wm = wid >> 1, wn = wid & 1;

    // XCD-aware swizzle: 256 blocks = 8 XCDs x 32; each XCD owns a 4(m) x 8(n) super-tile
    const int bid = blockIdx.x;
    const int xcd = bid & 7, jj = bid >> 3;
    const int bm = (xcd & 1) * 4 + (jj & 3);
    const int bn = (xcd >> 1) * 8 + (jj >> 2);

    f32x4 acc[2][2];
#pragma unroll
    for (int a = 0; a < 2; ++a)
#pragma unroll
        for (int b = 0; b < 2; ++b) acc[a][b] = (f32x4)(0.0f);

    // --- staging: 4 matrices, 8KB each; wave w covers 1KB chunks {w, w+4} ---
    auto stage4 = [&](int buf, int k0) {
#pragma unroll
        for (int cc = 0; cc < 2; ++cc) {
            int c = wid + cc * 4;
            int row = c * 8 + (li >> 3);
            int clog = (li & 7) ^ (row & 7);  // XOR chunk swizzle (involution)
            int ga = (bm * 64 + row) * DDIM + k0 + clog * 8;
            int gw = (bn * 64 + row) * DDIM + k0 + clog * 8;
            int lo = c * 512 + li * 8;
            glds16(Ah + ga, &lds[buf][0][lo]);
            glds16(Al + ga, &lds[buf][1][lo]);
            glds16(Wh + gw, &lds[buf][2][lo]);
            glds16(Wl + gw, &lds[buf][3][lo]);
        }
    };

    auto rdfrag = [&](int buf, int mat, int rbase, int ks) -> half8 {
        int r = rbase + (li & 15);
        int cl = ks * 4 + (li >> 4);
        int off = r * 64 + ((cl ^ (r & 7)) << 3);
        return *(const half8*)&lds[buf][mat][off];
    };

    auto compute = [&](int buf) {
#pragma unroll
        for (int ks = 0; ks < 2; ++ks) {
            half8 ah[2], al[2], bh[2], bl[2];
#pragma unroll
            for (int f = 0; f < 2; ++f) {
                ah[f] = rdfrag(buf, 0, wm * 32 + f * 16, ks);
                al[f] = rdfrag(buf, 1, wm * 32 + f * 16, ks);
                bh[f] = rdfrag(buf, 2, wn * 32 + f * 16, ks);
                bl[f] = rdfrag(buf, 3, wn * 32 + f * 16, ks);
            }
#pragma unroll
            for (int mi = 0; mi < 2; ++mi)
#pragma unroll
                for (int ni = 0; ni < 2; ++ni) {
                    acc[mi][ni] = __builtin_amdgcn_mfma_f32_16x16x32_f16(ah[mi], bh[ni],
                                                                         acc[mi][ni], 0, 0, 0);
                    acc[mi][ni] = __builtin_amdgcn_mfma_f32_16x16x32_f16(ah[mi], bl[ni],
                                                                         acc[mi][ni], 0, 0, 0);
                    acc[mi][ni] = __builtin_amdgcn_mfma_f32_16x16x32_f16(al[mi], bh[ni],
                                                                         acc[mi][ni], 0, 0, 0);
                }
        }
    };

    // --- 2-phase pipelined K loop: 32 k-tiles of BK=64 ---
    stage4(0, 0);
    asm volatile("s_waitcnt vmcnt(0)" ::: "memory");
    __builtin_amdgcn_s_barrier();
    for (int kt = 0; kt < 32; ++kt) {
        int buf = kt & 1;
        if (kt + 1 < 32) stage4(buf ^ 1, (kt + 1) * 64);
        compute(buf);
        asm volatile("s_waitcnt vmcnt(0)" ::: "memory");
        __builtin_amdgcn_s_barrier();
    }

    // --- fused epilogue ---
    const float dt = scal[SC_DT];
    const int lrow = li >> 4, lcol = li & 15;
    const float bias0 = bias[bn * 64 + wn * 32 + lcol];
    const float bias1 = bias[bn * 64 + wn * 32 + 16 + lcol];
    float lerr = 0.0f, lsp = 0.0f;

#pragma unroll
    for (int mi = 0; mi < 2; ++mi) {
#pragma unroll
        for (int r = 0; r < 4; ++r) {
            int m = bm * 64 + wm * 32 + mi * 16 + lrow * 4 + r;
            size_t base = (size_t)m * DDIM;
#pragma unroll
            for (int ni = 0; ni < 2; ++ni) {
                int n = bn * 64 + wn * 32 + ni * 16 + lcol;
                size_t idx = base + n;
                float accv = acc[mi][ni][r] + (ni == 0 ? bias0 : bias1);
                float xv = xg[idx];
                float lk1 = 0.f, lk2 = 0.f, lk3 = 0.f, lk4 = 0.f, lk5 = 0.f;
                if constexpr (S >= 2) lk1 = gk1[idx];
                if constexpr (S >= 3) lk2 = gk2[idx];
                if constexpr (S >= 4) lk3 = gk3[idx];
                if constexpr (S >= 5) lk4 = gk4[idx];
                if constexpr (S >= 6) lk5 = gk5[idx];
                // recompute this stage's xs for the reflect-sign
                float xs;
                if constexpr (S == 1) xs = xv;
                if constexpr (S == 2) xs = xv + dt * (0.25f * lk1);
                if constexpr (S == 3)
                    xs = xv + dt * ((float)(3.0 / 32.0) * lk1 + (float)(9.0 / 32.0) * lk2);
                if constexpr (S == 4)
                    xs = xv + dt * ((float)(1932.0 / 2197.0) * lk1 +
                                    (float)(-7200.0 / 2197.0) * lk2 +
                                    (float)(7296.0 / 2197.0) * lk3);
                if constexpr (S == 5)
                    xs = xv + dt * ((float)(439.0 / 216.0) * lk1 - 8.0f * lk2 +
                                    (float)(3680.0 / 513.0) * lk3 +
                                    (float)(-845.0 / 4104.0) * lk4);
                if constexpr (S == 6)
                    xs = xv + dt * ((float)(-8.0 / 27.0) * lk1 + 2.0f * lk2 +
                                    (float)(-3544.0 / 2565.0) * lk3 +
                                    (float)(1859.0 / 4104.0) * lk4 + (float)(-11.0 / 40.0) * lk5);
                float sgn = (((int)xs) & 1) ? -1.0f : 1.0f;
                float kv = sgn * accv;
                if constexpr (S < 6) kout[idx] = kv;
                if constexpr (S < 6) {
                    // next stage's xs -> split-f16 A
                    float xn;
                    if constexpr (S == 1) xn = xv + dt * (0.25f * kv);
                    if constexpr (S == 2)
                        xn = xv + dt * ((float)(3.0 / 32.0) * lk1 + (float)(9.0 / 32.0) * kv);
                    if constexpr (S == 3)
                        xn = xv + dt * ((float)(1932.0 / 2197.0) * lk1 +
                                        (float)(-7200.0 / 2197.0) * lk2 +
                                        (float)(7296.0 / 2197.0) * kv);
                    if constexpr (S == 4)
                        xn = xv + dt * ((float)(439.0 / 216.0) * lk1 - 8.0f * lk2 +
                                        (float)(3680.0 / 513.0) * lk3 +
                                        (float)(-845.0 / 4104.0) * kv);
                    if constexpr (S == 5)
                        xn = xv + dt * ((float)(-8.0 / 27.0) * lk1 + 2.0f * lk2 +
                                        (float)(-3544.0 / 2565.0) * lk3 +
                                        (float)(1859.0 / 4104.0) * lk4 +
                                        (float)(-11.0 / 40.0) * kv);
                    float y = reflect_f(xn);
                    _Float16 hh, ll;
                    split_f16(y, hh, ll);
                    Aoh[idx] = hh;
                    Aol[idx] = ll;
                } else {
                    float x5 = xv + dt * ((float)(16.0 / 135.0) * lk1 +
                                          (float)(6656.0 / 12825.0) * lk3 +
                                          (float)(28561.0 / 56430.0) * lk4 +
                                          (float)(-9.0 / 50.0) * lk5 + (float)(2.0 / 55.0) * kv);
                    float x4 = xv + dt * ((float)(25.0 / 216.0) * lk1 +
                                          (float)(1408.0 / 2565.0) * lk3 +
                                          (float)(2197.0 / 4104.0) * lk4 +
                                          (float)(-1.0 / 5.0) * lk5);
                    lerr = fmaxf(lerr, fabsf(x5 - x4));
                    lsp = fmaxf(lsp, fabsf(x5 - xv));
                    x5out[idx] = x5;
                }
            }
        }
    }

    if constexpr (S == 6) {
#pragma unroll
        for (int off = 32; off > 0; off >>= 1) {
            lerr = fmaxf(lerr, __shfl_down(lerr, off));
            lsp = fmaxf(lsp, __shfl_down(lsp, off));
        }
        if (li == 0) {
            serr[wid] = lerr;
            ssp[wid] = lsp;
        }
        __syncthreads();
        if (tid == 0) {
            float e = fmaxf(fmaxf(serr[0], serr[1]), fmaxf(serr[2], serr[3]));
            float s = fmaxf(fmaxf(ssp[0], ssp[1]), fmaxf(ssp[2], ssp[3]));
            atomicMax((unsigned int*)&scal[SC_ERR], __float_as_uint(e));
            atomicMax((unsigned int*)&scal[SC_SP], __float_as_uint(s));
        }
    }
}

// ---------------- scalar update & commit ----------------

__global__ void scalar_update(float* scal) {
    if (threadIdx.x == 0 && blockIdx.x == 0) {
        float dt = scal[SC_DT];
        float err = scal[SC_ERR];
        float spmax = scal[SC_SP];
        unsigned int done = ((unsigned int*)scal)[SC_DONE];
        bool accept = err < TOLF;
        bool step = accept && (done == 0u);
        float speed = spmax / dt;
        unsigned int done_new = (done || (step && (speed < SPEED_TOLF))) ? 1u : 0u;
        float scale = 0.9f * powf(TOLF / (err + 1e-12f), 0.2f);
        scale = fminf(fmaxf(scale, 0.1f), 4.0f);
        float dtn = fmaxf(dt * scale, MIN_DTF);
        scal[SC_DT] = done ? dt : dtn;
        ((unsigned int*)scal)[SC_DONE] = done_new;
        ((unsigned int*)scal)[SC_COMMIT] = step ? 1u : 0u;
        scal[SC_ERR] = 0.0f;
        scal[SC_SP] = 0.0f;
    }
}

__global__ void commit_prep(float* __restrict__ x, const float* __restrict__ x5,
                            _Float16* __restrict__ Ah, _Float16* __restrict__ Al,
                            const float* __restrict__ scal) {
    bool com = ((const unsigned int*)scal)[SC_COMMIT] != 0u;
    int tid = blockIdx.x * blockDim.x + threadIdx.x;
    float4* X = (float4*)x;
    const float4* X5 = (const float4*)x5;
    for (int i = tid; i < NV4; i += gridDim.x * blockDim.x) {
        float4 v = com ? X5[i] : X[i];
        if (com) X[i] = v;
        half4v h, l;
        float vv[4] = {v.x, v.y, v.z, v.w};
#pragma unroll
        for (int q = 0; q < 4; ++q) {
            float y = reflect_f(vv[q]);
            _Float16 hh, ll;
            split_f16(y, hh, ll);
            h[q] = hh;
            l[q] = ll;
        }
        *(half4v*)&Ah[(size_t)i * 4] = h;
        *(half4v*)&Al[(size_t)i * 4] = l;
    }
}

// ---------------- launch ----------------

extern "C" void kernel_launch(void* const* d_in, const int* in_sizes, int n_in, void* d_out,
                              int out_size, void* d_ws, size_t ws_size, hipStream_t stream) {
    const float* x0 = (const float*)d_in[0];
    const float* W = (const float*)d_in[1];
    const float* bias = (const float*)d_in[2];
    float* x = (float*)d_out;

    float* ws = (float*)d_ws;
    float* k1 = ws + 0 * (size_t)NELEM;
    float* k2 = ws + 1 * (size_t)NELEM;
    float* k3 = ws + 2 * (size_t)NELEM;
    float* k4 = ws + 3 * (size_t)NELEM;
    float* k5 = ws + 4 * (size_t)NELEM;
    float* x5 = ws + 5 * (size_t)NELEM;
    float* scal = ws + 6 * (size_t)NELEM;
    _Float16* hb = (_Float16*)(ws + 6 * (size_t)NELEM + 64);
    _Float16* A0h = hb + 0 * (size_t)NELEM;
    _Float16* A0l = hb + 1 * (size_t)NELEM;
    _Float16* A1h = hb + 2 * (size_t)NELEM;
    _Float16* A1l = hb + 3 * (size_t)NELEM;
    _Float16* Wh = hb + 4 * (size_t)NELEM;
    _Float16* Wl = Wh + (size_t)DDIM * DDIM;

    wconv_kernel<<<2048, 256, 0, stream>>>(W, Wh, Wl);
    init_kernel<<<1024, 256, 0, stream>>>(x0, x, A1h, A1l, scal);

    for (int it = 0; it < 32; ++it) {
        stage_kernel<1><<<256, 256, 0, stream>>>(A1h, A1l, A0h, A0l, Wh, Wl, bias, x, k1, k2, k3,
                                                 k4, k5, k1, x5, scal);
        stage_kernel<2><<<256, 256, 0, stream>>>(A0h, A0l, A1h, A1l, Wh, Wl, bias, x, k1, k2, k3,
                                                 k4, k5, k2, x5, scal);
        stage_kernel<3><<<256, 256, 0, stream>>>(A1h, A1l, A0h, A0l, Wh, Wl, bias, x, k1, k2, k3,
                                                 k4, k5, k3, x5, scal);
        stage_kernel<4><<<256, 256, 0, stream>>>(A0h, A0l, A1h, A1l, Wh, Wl, bias, x, k1, k2, k3,
                                                 k4, k5, k4, x5, scal);
        stage_kernel<5><<<256, 256, 0, stream>>>(A1h, A1l, A0h, A0l, Wh, Wl, bias, x, k1, k2, k3,
                                                 k4, k5, k5, x5, scal);
        stage_kernel<6><<<256, 256, 0, stream>>>(A0h, A0l, A1h, A1l, Wh, Wl, bias, x, k1, k2, k3,
                                                 k4, k5, k1, x5, scal);
        scalar_update<<<1, 64, 0, stream>>>(scal);
        commit_prep<<<1024, 256, 0, stream>>>(x, x5, A1h, A1l, scal);
    }
}

// Round 3
// 4138.517 us; speedup vs baseline: 5.9136x; 1.3577x over previous
//
#include <hip/hip_runtime.h>

#define DDIM 2048
#define BDIM 512
#define NELEM (BDIM * DDIM)
#define NV4 (NELEM / 4)
#define NW4 (DDIM * DDIM / 4)

#define SC_DT 0
#define SC_DONE 1
#define SC_ERR 2
#define SC_SP 3
#define SC_COMMIT 4

#define TOLF 0.01f
#define MIN_DTF 0.1f
#define SPEED_TOLF 1e-3f

typedef _Float16 half8 __attribute__((ext_vector_type(8)));
typedef _Float16 half4v __attribute__((ext_vector_type(4)));
typedef float f32x4 __attribute__((ext_vector_type(4)));

__device__ __forceinline__ void glds16(const _Float16* g, _Float16* l) {
    __builtin_amdgcn_global_load_lds((__attribute__((address_space(1))) void*)g,
                                     (__attribute__((address_space(3))) void*)l, 16, 0, 0);
}

__device__ __forceinline__ void split_f16(float y, _Float16& h, _Float16& l) {
    h = (_Float16)y;
    l = (_Float16)(y - (float)h);
}

__device__ __forceinline__ float reflect_f(float v) {
    int i = (int)v;
    return ((i & 1) == 0) ? v : 1.0f - v;
}

// ---------------- init / conversion kernels ----------------

__global__ void wconv_kernel(const float* __restrict__ W, _Float16* __restrict__ Wh,
                             _Float16* __restrict__ Wl) {
    int tid = blockIdx.x * blockDim.x + threadIdx.x;
    const float4* Wv = (const float4*)W;
    for (int i = tid; i < NW4; i += gridDim.x * blockDim.x) {
        float4 v = Wv[i];
        half4v h, l;
        float vv[4] = {v.x, v.y, v.z, v.w};
#pragma unroll
        for (int q = 0; q < 4; ++q) {
            _Float16 hh, ll;
            split_f16(vv[q], hh, ll);
            h[q] = hh;
            l[q] = ll;
        }
        *(half4v*)&Wh[(size_t)i * 4] = h;
        *(half4v*)&Wl[(size_t)i * 4] = l;
    }
}

__global__ void init_kernel(const float* __restrict__ x0, float* __restrict__ x,
                            _Float16* __restrict__ Ah, _Float16* __restrict__ Al,
                            float* __restrict__ scal) {
    int tid = blockIdx.x * blockDim.x + threadIdx.x;
    const float4* X0 = (const float4*)x0;
    float4* X = (float4*)x;
    for (int i = tid; i < NV4; i += gridDim.x * blockDim.x) {
        float4 v = X0[i];
        X[i] = v;
        half4v h, l;
        float vv[4] = {v.x, v.y, v.z, v.w};
#pragma unroll
        for (int q = 0; q < 4; ++q) {
            float y = reflect_f(vv[q]);
            _Float16 hh, ll;
            split_f16(y, hh, ll);
            h[q] = hh;
            l[q] = ll;
        }
        *(half4v*)&Ah[(size_t)i * 4] = h;
        *(half4v*)&Al[(size_t)i * 4] = l;
    }
    if (tid == 0) {
        scal[SC_DT] = 0.1f;
        ((unsigned int*)scal)[SC_DONE] = 0u;
        scal[SC_ERR] = 0.0f;
        scal[SC_SP] = 0.0f;
        ((unsigned int*)scal)[SC_COMMIT] = 0u;
    }
}

// ---------------- fused stage GEMM (K-split, 8 waves) ----------------
// kS = sign(xs_S) * (G(xs_S) @ W + bias) via 3-pass split-f16 MFMA.
// Waves 0-3 integrate k in [0,1024), waves 4-7 k in [1024,2048); partial
// accumulators are exchanged through LDS; each group finalizes 16 of the
// 32 rows of its wave tile (group g handles the mi==g 16-row band).

template <int S>
__global__ __launch_bounds__(512, 2) void stage_kernel(
    const _Float16* __restrict__ Ah, const _Float16* __restrict__ Al,
    _Float16* __restrict__ Aoh, _Float16* __restrict__ Aol, const _Float16* __restrict__ Wh,
    const _Float16* __restrict__ Wl, const float* __restrict__ bias,
    const float* __restrict__ xg, const float* __restrict__ gk1, const float* __restrict__ gk2,
    const float* __restrict__ gk3, const float* __restrict__ gk4, const float* __restrict__ gk5,
    float* __restrict__ kout, float* __restrict__ x5out, float* __restrict__ scal) {
    __shared__ __align__(16) _Float16 lds[2][2][4][64 * 64];  // [kgroup][buf][Ah,Al,Wh,Wl][...]
    __shared__ float serr[8], ssp[8];

    const int tid = threadIdx.x;
    const int li = tid & 63;
    const int wid = tid >> 6;       // 0..7
    const int g = wid >> 2;         // k-split group
    const int w4 = wid & 3;         // wave-in-group
    const int wm = w4 >> 1, wn = w4 & 1;

    // XCD-aware swizzle: 256 blocks = 8 XCDs x 32; each XCD owns a 4(m) x 8(n) super-tile
    const int bid = blockIdx.x;
    const int xcd = bid & 7, jj = bid >> 3;
    const int bm = (xcd & 1) * 4 + (jj & 3);
    const int bn = (xcd >> 1) * 8 + (jj >> 2);

    f32x4 acc[2][2];
#pragma unroll
    for (int a = 0; a < 2; ++a)
#pragma unroll
        for (int b = 0; b < 2; ++b) acc[a][b] = (f32x4)(0.0f);

    // staging: 4 matrices x 8KB per k-tile, by this group's 4 waves (8 glds/thread)
    auto stage4 = [&](int buf, int k0) {
#pragma unroll
        for (int cc = 0; cc < 2; ++cc) {
            int c = w4 + cc * 4;
            int row = c * 8 + (li >> 3);
            int clog = (li & 7) ^ (row & 7);  // XOR chunk swizzle (involution)
            int ga = (bm * 64 + row) * DDIM + k0 + clog * 8;
            int gw = (bn * 64 + row) * DDIM + k0 + clog * 8;
            int lo = c * 512 + li * 8;
            glds16(Ah + ga, &lds[g][buf][0][lo]);
            glds16(Al + ga, &lds[g][buf][1][lo]);
            glds16(Wh + gw, &lds[g][buf][2][lo]);
            glds16(Wl + gw, &lds[g][buf][3][lo]);
        }
    };

    auto rdfrag = [&](int buf, int mat, int rbase, int ks) -> half8 {
        int r = rbase + (li & 15);
        int cl = ks * 4 + (li >> 4);
        int off = r * 64 + ((cl ^ (r & 7)) << 3);
        return *(const half8*)&lds[g][buf][mat][off];
    };

    auto compute = [&](int buf) {
#pragma unroll
        for (int ks = 0; ks < 2; ++ks) {
            half8 ah[2], al[2], bh[2], bl[2];
#pragma unroll
            for (int f = 0; f < 2; ++f) {
                ah[f] = rdfrag(buf, 0, wm * 32 + f * 16, ks);
                al[f] = rdfrag(buf, 1, wm * 32 + f * 16, ks);
                bh[f] = rdfrag(buf, 2, wn * 32 + f * 16, ks);
                bl[f] = rdfrag(buf, 3, wn * 32 + f * 16, ks);
            }
#pragma unroll
            for (int mi = 0; mi < 2; ++mi)
#pragma unroll
                for (int ni = 0; ni < 2; ++ni) {
                    acc[mi][ni] = __builtin_amdgcn_mfma_f32_16x16x32_f16(ah[mi], bh[ni],
                                                                         acc[mi][ni], 0, 0, 0);
                    acc[mi][ni] = __builtin_amdgcn_mfma_f32_16x16x32_f16(ah[mi], bl[ni],
                                                                         acc[mi][ni], 0, 0, 0);
                    acc[mi][ni] = __builtin_amdgcn_mfma_f32_16x16x32_f16(al[mi], bh[ni],
                                                                         acc[mi][ni], 0, 0, 0);
                }
        }
    };

    // --- pipelined K loop: 16 k-tiles of BK=64 per group, counted vmcnt ---
    const int kbase = g * 1024;
    stage4(0, kbase);
#pragma unroll 2
    for (int t = 0; t < 16; ++t) {
        if (t + 1 < 16) {
            stage4((t + 1) & 1, kbase + (t + 1) * 64);
            asm volatile("s_waitcnt vmcnt(8)" ::: "memory");
        } else {
            asm volatile("s_waitcnt vmcnt(0)" ::: "memory");
        }
        __builtin_amdgcn_sched_barrier(0);
        __builtin_amdgcn_s_barrier();
        compute(t & 1);
        __builtin_amdgcn_s_barrier();
    }

    // --- partial-sum exchange: group g keeps the mi==g band, ships the other ---
    float4* xch = (float4*)&lds[0][0][0][0];
#pragma unroll
    for (int ni = 0; ni < 2; ++ni) {
        int slot = ((g * 4 + w4) * 2 + ni) * 64 + li;
        if (g == 0)
            xch[slot] = make_float4(acc[1][ni][0], acc[1][ni][1], acc[1][ni][2], acc[1][ni][3]);
        else
            xch[slot] = make_float4(acc[0][ni][0], acc[0][ni][1], acc[0][ni][2], acc[0][ni][3]);
    }
    __syncthreads();
    f32x4 fin[2];
#pragma unroll
    for (int ni = 0; ni < 2; ++ni) {
        int slot = (((1 - g) * 4 + w4) * 2 + ni) * 64 + li;
        float4 p = xch[slot];
        f32x4 mine = (g == 0) ? acc[0][ni] : acc[1][ni];
        mine[0] += p.x;
        mine[1] += p.y;
        mine[2] += p.z;
        mine[3] += p.w;
        fin[ni] = mine;
    }

    // --- fused epilogue: each thread finalizes 8 elems (rows wm*32+g*16+..) ---
    const float dt = scal[SC_DT];
    const int lrow = li >> 4, lcol = li & 15;
    const float bias0 = bias[bn * 64 + wn * 32 + lcol];
    const float bias1 = bias[bn * 64 + wn * 32 + 16 + lcol];
    float lerr = 0.0f, lsp = 0.0f;

#pragma unroll
    for (int r = 0; r < 4; ++r) {
        int m = bm * 64 + wm * 32 + g * 16 + lrow * 4 + r;
        size_t base = (size_t)m * DDIM;
#pragma unroll
        for (int ni = 0; ni < 2; ++ni) {
            int n = bn * 64 + wn * 32 + ni * 16 + lcol;
            size_t idx = base + n;
            float accv = fin[ni][r] + (ni == 0 ? bias0 : bias1);
            float xv = xg[idx];
            float lk1 = 0.f, lk2 = 0.f, lk3 = 0.f, lk4 = 0.f, lk5 = 0.f;
            if constexpr (S >= 2) lk1 = gk1[idx];
            if constexpr (S >= 3) lk2 = gk2[idx];
            if constexpr (S >= 4) lk3 = gk3[idx];
            if constexpr (S >= 5) lk4 = gk4[idx];
            if constexpr (S >= 6) lk5 = gk5[idx];
            // recompute this stage's xs for the reflect-sign
            float xs;
            if constexpr (S == 1) xs = xv;
            if constexpr (S == 2) xs = xv + dt * (0.25f * lk1);
            if constexpr (S == 3)
                xs = xv + dt * ((float)(3.0 / 32.0) * lk1 + (float)(9.0 / 32.0) * lk2);
            if constexpr (S == 4)
                xs = xv + dt * ((float)(1932.0 / 2197.0) * lk1 + (float)(-7200.0 / 2197.0) * lk2 +
                                (float)(7296.0 / 2197.0) * lk3);
            if constexpr (S == 5)
                xs = xv + dt * ((float)(439.0 / 216.0) * lk1 - 8.0f * lk2 +
                                (float)(3680.0 / 513.0) * lk3 + (float)(-845.0 / 4104.0) * lk4);
            if constexpr (S == 6)
                xs = xv + dt * ((float)(-8.0 / 27.0) * lk1 + 2.0f * lk2 +
                                (float)(-3544.0 / 2565.0) * lk3 + (float)(1859.0 / 4104.0) * lk4 +
                                (float)(-11.0 / 40.0) * lk5);
            float sgn = (((int)xs) & 1) ? -1.0f : 1.0f;
            float kv = sgn * accv;
            if constexpr (S < 6) {
                kout[idx] = kv;
                float xn;
                if constexpr (S == 1) xn = xv + dt * (0.25f * kv);
                if constexpr (S == 2)
                    xn = xv + dt * ((float)(3.0 / 32.0) * lk1 + (float)(9.0 / 32.0) * kv);
                if constexpr (S == 3)
                    xn = xv + dt * ((float)(1932.0 / 2197.0) * lk1 +
                                    (float)(-7200.0 / 2197.0) * lk2 + (float)(7296.0 / 2197.0) * kv);
                if constexpr (S == 4)
                    xn = xv + dt * ((float)(439.0 / 216.0) * lk1 - 8.0f * lk2 +
                                    (float)(3680.0 / 513.0) * lk3 + (float)(-845.0 / 4104.0) * kv);
                if constexpr (S == 5)
                    xn = xv + dt * ((float)(-8.0 / 27.0) * lk1 + 2.0f * lk2 +
                                    (float)(-3544.0 / 2565.0) * lk3 +
                                    (float)(1859.0 / 4104.0) * lk4 + (float)(-11.0 / 40.0) * kv);
                float y = reflect_f(xn);
                _Float16 hh, ll;
                split_f16(y, hh, ll);
                Aoh[idx] = hh;
                Aol[idx] = ll;
            } else {
                float x5 = xv + dt * ((float)(16.0 / 135.0) * lk1 + (float)(6656.0 / 12825.0) * lk3 +
                                      (float)(28561.0 / 56430.0) * lk4 + (float)(-9.0 / 50.0) * lk5 +
                                      (float)(2.0 / 55.0) * kv);
                float x4 = xv + dt * ((float)(25.0 / 216.0) * lk1 + (float)(1408.0 / 2565.0) * lk3 +
                                      (float)(2197.0 / 4104.0) * lk4 + (float)(-1.0 / 5.0) * lk5);
                lerr = fmaxf(lerr, fabsf(x5 - x4));
                lsp = fmaxf(lsp, fabsf(x5 - xv));
                x5out[idx] = x5;
            }
        }
    }

    if constexpr (S == 6) {
#pragma unroll
        for (int off = 32; off > 0; off >>= 1) {
            lerr = fmaxf(lerr, __shfl_down(lerr, off));
            lsp = fmaxf(lsp, __shfl_down(lsp, off));
        }
        if (li == 0) {
            serr[wid] = lerr;
            ssp[wid] = lsp;
        }
        __syncthreads();
        if (tid == 0) {
            float e = serr[0], s = ssp[0];
#pragma unroll
            for (int w = 1; w < 8; ++w) {
                e = fmaxf(e, serr[w]);
                s = fmaxf(s, ssp[w]);
            }
            atomicMax((unsigned int*)&scal[SC_ERR], __float_as_uint(e));
            atomicMax((unsigned int*)&scal[SC_SP], __float_as_uint(s));
        }
    }
}

// ---------------- scalar update & commit ----------------

__global__ void scalar_update(float* scal) {
    if (threadIdx.x == 0 && blockIdx.x == 0) {
        float dt = scal[SC_DT];
        float err = scal[SC_ERR];
        float spmax = scal[SC_SP];
        unsigned int done = ((unsigned int*)scal)[SC_DONE];
        bool accept = err < TOLF;
        bool step = accept && (done == 0u);
        float speed = spmax / dt;
        unsigned int done_new = (done || (step && (speed < SPEED_TOLF))) ? 1u : 0u;
        float scale = 0.9f * powf(TOLF / (err + 1e-12f), 0.2f);
        scale = fminf(fmaxf(scale, 0.1f), 4.0f);
        float dtn = fmaxf(dt * scale, MIN_DTF);
        scal[SC_DT] = done ? dt : dtn;
        ((unsigned int*)scal)[SC_DONE] = done_new;
        ((unsigned int*)scal)[SC_COMMIT] = step ? 1u : 0u;
        scal[SC_ERR] = 0.0f;
        scal[SC_SP] = 0.0f;
    }
}

__global__ void commit_prep(float* __restrict__ x, const float* __restrict__ x5,
                            _Float16* __restrict__ Ah, _Float16* __restrict__ Al,
                            const float* __restrict__ scal) {
    bool com = ((const unsigned int*)scal)[SC_COMMIT] != 0u;
    int tid = blockIdx.x * blockDim.x + threadIdx.x;
    float4* X = (float4*)x;
    const float4* X5 = (const float4*)x5;
    for (int i = tid; i < NV4; i += gridDim.x * blockDim.x) {
        float4 v = com ? X5[i] : X[i];
        if (com) X[i] = v;
        half4v h, l;
        float vv[4] = {v.x, v.y, v.z, v.w};
#pragma unroll
        for (int q = 0; q < 4; ++q) {
            float y = reflect_f(vv[q]);
            _Float16 hh, ll;
            split_f16(y, hh, ll);
            h[q] = hh;
            l[q] = ll;
        }
        *(half4v*)&Ah[(size_t)i * 4] = h;
        *(half4v*)&Al[(size_t)i * 4] = l;
    }
}

// ---------------- launch ----------------

extern "C" void kernel_launch(void* const* d_in, const int* in_sizes, int n_in, void* d_out,
                              int out_size, void* d_ws, size_t ws_size, hipStream_t stream) {
    const float* x0 = (const float*)d_in[0];
    const float* W = (const float*)d_in[1];
    const float* bias = (const float*)d_in[2];
    float* x = (float*)d_out;

    float* ws = (float*)d_ws;
    float* k1 = ws + 0 * (size_t)NELEM;
    float* k2 = ws + 1 * (size_t)NELEM;
    float* k3 = ws + 2 * (size_t)NELEM;
    float* k4 = ws + 3 * (size_t)NELEM;
    float* k5 = ws + 4 * (size_t)NELEM;
    float* x5 = ws + 5 * (size_t)NELEM;
    float* scal = ws + 6 * (size_t)NELEM;
    _Float16* hb = (_Float16*)(ws + 6 * (size_t)NELEM + 64);
    _Float16* A0h = hb + 0 * (size_t)NELEM;
    _Float16* A0l = hb + 1 * (size_t)NELEM;
    _Float16* A1h = hb + 2 * (size_t)NELEM;
    _Float16* A1l = hb + 3 * (size_t)NELEM;
    _Float16* Wh = hb + 4 * (size_t)NELEM;
    _Float16* Wl = Wh + (size_t)DDIM * DDIM;

    wconv_kernel<<<2048, 256, 0, stream>>>(W, Wh, Wl);
    init_kernel<<<1024, 256, 0, stream>>>(x0, x, A1h, A1l, scal);

    for (int it = 0; it < 32; ++it) {
        stage_kernel<1><<<256, 512, 0, stream>>>(A1h, A1l, A0h, A0l, Wh, Wl, bias, x, k1, k2, k3,
                                                 k4, k5, k1, x5, scal);
        stage_kernel<2><<<256, 512, 0, stream>>>(A0h, A0l, A1h, A1l, Wh, Wl, bias, x, k1, k2, k3,
                                                 k4, k5, k2, x5, scal);
        stage_kernel<3><<<256, 512, 0, stream>>>(A1h, A1l, A0h, A0l, Wh, Wl, bias, x, k1, k2, k3,
                                                 k4, k5, k3, x5, scal);
        stage_kernel<4><<<256, 512, 0, stream>>>(A0h, A0l, A1h, A1l, Wh, Wl, bias, x, k1, k2, k3,
                                                 k4, k5, k4, x5, scal);
        stage_kernel<5><<<256, 512, 0, stream>>>(A1h, A1l, A0h, A0l, Wh, Wl, bias, x, k1, k2, k3,
                                                 k4, k5, k5, x5, scal);
        stage_kernel<6><<<256, 512, 0, stream>>>(A0h, A0l, A1h, A1l, Wh, Wl, bias, x, k1, k2, k3,
                                                 k4, k5, k1, x5, scal);
        scalar_update<<<1, 64, 0, stream>>>(scal);
        commit_prep<<<1024, 256, 0, stream>>>(x, x5, A1h, A1l, scal);
    }
}